// Round 8
// baseline (264.954 us; speedup 1.0000x reference)
//
#include <hip/hip_runtime.h>
#include <math.h>

#define BB 2
#define VV 768
#define HID 128
#define NH 8
#define HD 16

typedef float f4v __attribute__((ext_vector_type(4)));

// ---------------------------------------------------------------------------
// Kernel 1: q/k/v = x @ W^T + b, head-major layout ((b*NH+h)*VV+v)*HD+d.
// 256 threads = 2 x-rows per block.
// ---------------------------------------------------------------------------
__global__ __launch_bounds__(256) void qkv_kernel(
    const float* __restrict__ x,
    const float* __restrict__ Wq, const float* __restrict__ bq,
    const float* __restrict__ Wk, const float* __restrict__ bk,
    const float* __restrict__ Wv, const float* __restrict__ bv,
    float* __restrict__ qh, float* __restrict__ kh, float* __restrict__ vh) {
    __shared__ float xs[2][HID];
    const int half = threadIdx.x >> 7;
    const int c    = threadIdx.x & 127;
    const int row  = blockIdx.x * 2 + half;      // 0..1535
    xs[half][c] = x[row * HID + c];
    __syncthreads();
    const float4* xs4 = (const float4*)xs[half];
    const float4* wq4 = (const float4*)(Wq + c * HID);
    const float4* wk4 = (const float4*)(Wk + c * HID);
    const float4* wv4 = (const float4*)(Wv + c * HID);
    float aq = 0.f, ak = 0.f, av = 0.f;
#pragma unroll
    for (int k4 = 0; k4 < HID / 4; ++k4) {
        float4 xv = xs4[k4];
        float4 a = wq4[k4];
        aq += xv.x * a.x + xv.y * a.y + xv.z * a.z + xv.w * a.w;
        float4 bv2 = wk4[k4];
        ak += xv.x * bv2.x + xv.y * bv2.y + xv.z * bv2.z + xv.w * bv2.w;
        float4 cv = wv4[k4];
        av += xv.x * cv.x + xv.y * cv.y + xv.z * cv.z + xv.w * cv.w;
    }
    const int b = row / VV, vi = row - b * VV;
    const int idx = ((b * NH + (c >> 4)) * VV + vi) * HD + (c & 15);
    qh[idx] = aq + bq[c];
    kh[idx] = ak + bk[c];
    vh[idx] = av + bv[c];
}

// ---------------------------------------------------------------------------
// Kernel 2 (fused): one block per (b,q) query row.
// Phase 1: mean the 768x128 edge slice -> mask_lds[768]. Reads are inline-asm
//   global_load_dwordx4 with sc0 (bypass L1 miss-tracking, the suspected
//   ~4.7KB/CU in-flight cap) + nt (one-touch stream), batched 8 per
//   vmcnt(0) drain: 8KB in flight per wave continuously.
// Phase 2: 4 waves x 2 heads: scores (q.k * 0.25 * mask) -> LDS, softmax,
//   P*V accumulate, 17-shuffle fold -> att_lds[128].
// Phase 3: out[b,q,:] = att_lds @ Wo^T + bo. No mask/att HBM round-trips.
// ---------------------------------------------------------------------------
__global__ __launch_bounds__(256) void fused_edge_attn_out(
    const float* __restrict__ eg,
    const float* __restrict__ qh, const float* __restrict__ kh,
    const float* __restrict__ vh,
    const float* __restrict__ Wo, const float* __restrict__ bo,
    float* __restrict__ out) {
    __shared__ float mask_lds[VV];       // 3 KB
    __shared__ float sc_lds[4][VV];      // 12 KB
    __shared__ float att_lds[HID];       // 0.5 KB

    const int lane = threadIdx.x & 63;
    const int wid  = threadIdx.x >> 6;           // wave 0..3
    const int bq   = blockIdx.x;                 // b*VV + q
    const int b    = bq / VV, q = bq - b * VV;

    // ---- phase 1: edge mean (each wave owns 192 contiguous rows = 96KB) ----
    {
        const float* wbase = eg + (size_t)bq * (VV * HID) + wid * (192 * HID);
#pragma unroll 1
        for (int batch = 0; batch < 12; ++batch) {
            const float* p0 = wbase + batch * 2048 + lane * 4;  // 8KB window
            const float* p1 = p0 + 1024;                        // +4KB
            f4v v0, v1, v2, v3, v4, v5, v6, v7;
            asm volatile(
                "global_load_dwordx4 %0, %8, off sc0 nt\n\t"
                "global_load_dwordx4 %1, %8, off offset:1024 sc0 nt\n\t"
                "global_load_dwordx4 %2, %8, off offset:2048 sc0 nt\n\t"
                "global_load_dwordx4 %3, %8, off offset:3072 sc0 nt\n\t"
                "global_load_dwordx4 %4, %9, off sc0 nt\n\t"
                "global_load_dwordx4 %5, %9, off offset:1024 sc0 nt\n\t"
                "global_load_dwordx4 %6, %9, off offset:2048 sc0 nt\n\t"
                "global_load_dwordx4 %7, %9, off offset:3072 sc0 nt\n\t"
                "s_waitcnt vmcnt(0)"
                : "=&v"(v0), "=&v"(v1), "=&v"(v2), "=&v"(v3),
                  "=&v"(v4), "=&v"(v5), "=&v"(v6), "=&v"(v7)
                : "v"(p0), "v"(p1));
            const int rbase = wid * 192 + batch * 16 + (lane >> 5);
            float s;
#define REDUCE_ROW(vi, i)                                                  \
            s = ((vi[0] + vi[1]) + (vi[2] + vi[3]));                       \
            s += __shfl_xor(s, 1);  s += __shfl_xor(s, 2);                 \
            s += __shfl_xor(s, 4);  s += __shfl_xor(s, 8);                 \
            s += __shfl_xor(s, 16);                                        \
            if ((lane & 31) == 0)                                          \
                mask_lds[rbase + 2 * (i)] = s * (1.0f / 128.0f);
            REDUCE_ROW(v0, 0) REDUCE_ROW(v1, 1) REDUCE_ROW(v2, 2) REDUCE_ROW(v3, 3)
            REDUCE_ROW(v4, 4) REDUCE_ROW(v5, 5) REDUCE_ROW(v6, 6) REDUCE_ROW(v7, 7)
#undef REDUCE_ROW
        }
    }
    __syncthreads();

    // ---- phase 2: attention, wave `wid` handles heads 2*wid, 2*wid+1 ----
#pragma unroll 1
    for (int hh = 0; hh < 2; ++hh) {
        const int h  = wid * 2 + hh;
        const int bh = b * NH + h;
        const float4* qp = (const float4*)(qh + ((size_t)bh * VV + q) * HD);
        const float4 q0 = qp[0], q1 = qp[1], q2 = qp[2], q3 = qp[3];
        const float* kbase = kh + (size_t)bh * VV * HD;
        const float* vbase = vh + (size_t)bh * VV * HD;

        float m = -INFINITY;
#pragma unroll
        for (int t = 0; t < VV / 64; ++t) {
            const int j = lane + 64 * t;
            const float4* kp = (const float4*)(kbase + j * HD);
            float4 k0 = kp[0], k1 = kp[1], k2 = kp[2], k3 = kp[3];
            float dot = q0.x * k0.x + q0.y * k0.y + q0.z * k0.z + q0.w * k0.w
                      + q1.x * k1.x + q1.y * k1.y + q1.z * k1.z + q1.w * k1.w
                      + q2.x * k2.x + q2.y * k2.y + q2.z * k2.z + q2.w * k2.w
                      + q3.x * k3.x + q3.y * k3.y + q3.z * k3.z + q3.w * k3.w;
            float s = dot * 0.25f * mask_lds[j];
            sc_lds[wid][j] = s;
            m = fmaxf(m, s);
        }
#pragma unroll
        for (int off = 1; off < 64; off <<= 1) m = fmaxf(m, __shfl_xor(m, off));

        float sum = 0.f;
        float acc[HD];
#pragma unroll
        for (int d = 0; d < HD; ++d) acc[d] = 0.f;
#pragma unroll
        for (int t = 0; t < VV / 64; ++t) {
            const int j = lane + 64 * t;
            float e = __expf(sc_lds[wid][j] - m);
            sum += e;
            const float4* vp = (const float4*)(vbase + j * HD);
            float4 v0 = vp[0], v1 = vp[1], v2 = vp[2], v3 = vp[3];
            acc[0]  += e * v0.x; acc[1]  += e * v0.y; acc[2]  += e * v0.z; acc[3]  += e * v0.w;
            acc[4]  += e * v1.x; acc[5]  += e * v1.y; acc[6]  += e * v1.z; acc[7]  += e * v1.w;
            acc[8]  += e * v2.x; acc[9]  += e * v2.y; acc[10] += e * v2.z; acc[11] += e * v2.w;
            acc[12] += e * v3.x; acc[13] += e * v3.y; acc[14] += e * v3.z; acc[15] += e * v3.w;
        }
#pragma unroll
        for (int off = 1; off < 64; off <<= 1) sum += __shfl_xor(sum, off);

        // exchange-and-halve fold (final: lane l holds d = bitrev4(l&15))
#pragma unroll
        for (int i = 0; i < 8; ++i) {
            float send = (lane & 1) ? acc[i] : acc[i + 8];
            float r = __shfl_xor(send, 1);
            acc[i] = ((lane & 1) ? acc[i + 8] : acc[i]) + r;
        }
#pragma unroll
        for (int i = 0; i < 4; ++i) {
            float send = (lane & 2) ? acc[i] : acc[i + 4];
            float r = __shfl_xor(send, 2);
            acc[i] = ((lane & 2) ? acc[i + 4] : acc[i]) + r;
        }
#pragma unroll
        for (int i = 0; i < 2; ++i) {
            float send = (lane & 4) ? acc[i] : acc[i + 2];
            float r = __shfl_xor(send, 4);
            acc[i] = ((lane & 4) ? acc[i + 2] : acc[i]) + r;
        }
        {
            float send = (lane & 8) ? acc[0] : acc[1];
            float r = __shfl_xor(send, 8);
            acc[0] = ((lane & 8) ? acc[1] : acc[0]) + r;
        }
        acc[0] += __shfl_xor(acc[0], 16);
        acc[0] += __shfl_xor(acc[0], 32);

        const int d = ((lane & 1) << 3) | ((lane & 2) << 1) | ((lane & 4) >> 1) | ((lane & 8) >> 3);
        if (lane < HD) att_lds[h * HD + d] = acc[0] / sum;
    }
    __syncthreads();

    // ---- phase 3: out[b,q,:] = att_lds @ Wo^T + bo ----
    if (threadIdx.x < HID) {
        const int c = threadIdx.x;
        const float4* a4 = (const float4*)att_lds;
        const float4* w4 = (const float4*)(Wo + c * HID);
        float a = 0.f;
#pragma unroll
        for (int k4 = 0; k4 < HID / 4; ++k4) {
            float4 xv = a4[k4];
            float4 wv = w4[k4];
            a += xv.x * wv.x + xv.y * wv.y + xv.z * wv.z + xv.w * wv.w;
        }
        out[(size_t)bq * HID + c] = a + bo[c];
    }
}

extern "C" void kernel_launch(void* const* d_in, const int* in_sizes, int n_in,
                              void* d_out, int out_size, void* d_ws, size_t ws_size,
                              hipStream_t stream) {
    const float* x  = (const float*)d_in[0];
    const float* eg = (const float*)d_in[1];
    const float* Wq = (const float*)d_in[2];
    const float* bq = (const float*)d_in[3];
    const float* Wk = (const float*)d_in[4];
    const float* bk = (const float*)d_in[5];
    const float* Wv = (const float*)d_in[6];
    const float* bv = (const float*)d_in[7];
    const float* Wo = (const float*)d_in[8];
    const float* bo = (const float*)d_in[9];
    float* out = (float*)d_out;

    float* ws = (float*)d_ws;
    float* qh = ws;                                // B*V*HID each
    float* kh = qh + (size_t)BB * VV * HID;
    float* vh = kh + (size_t)BB * VV * HID;

    hipLaunchKernelGGL(qkv_kernel, dim3(BB * VV / 2), dim3(256), 0, stream,
                       x, Wq, bq, Wk, bk, Wv, bv, qh, kh, vh);
    hipLaunchKernelGGL(fused_edge_attn_out, dim3(BB * VV), dim3(256), 0, stream,
                       eg, qh, kh, vh, Wo, bo, out);
}